// Round 7
// baseline (92.888 us; speedup 1.0000x reference)
//
#include <hip/hip_runtime.h>

// B=16, N=1024, M=8192.
//   d[b,n,m] = || binder[b,n,:] - target[m,:] ||
//   attract[b] = mean of 204 smallest (min_m d) over n;  repel[b] = sum relu(3-d)^2
//   out[b] = 10*attract + 5*repel
//
// R9 (R8 post-mortem: total 89.1us; rocprof exposed a 41.7us/iter 256MiB
// harness workspace re-poison fill (80% HBM) serialized in the timed loop --
// the invariant ~55us floor of all prior rounds. Pair ~27us, co-bound by
// VALU (~12.6us) and the per-CU LDS pipe (32 waves x 64 broadcast
// ds_read_b128 x ~12cy ~= 10us/CU)):
//  - targets are wave-uniform per iter -> move them to the SCALAR pipe:
//    transform kernel writes tt4[M] = (-2t, ||t||^2) to global (128KB,
//    L2-resident, shared across all b); pair loop reads via uniform address
//    -> s_load_dwordx4 on SMEM pipe. Zero LDS in the hot loop.
//  - fold parallelized into its own 256-block kernel (8MB at chip scale);
//    select kernel now only reads 64KB min_d2 + 8KB repel partials.
//  - still: no atomics, no memset, plain streaming stores.

#define BB 16
#define NN 1024
#define MM 8192
#define SL 128              // M-slices
#define MSL (MM / SL)       // 64 targets per slice
#define KSEL 204            // int(0.2 * 1024)

__global__ __launch_bounds__(256) void target_transform_kernel(
    const float* __restrict__ target,   // [M, 3]
    float4* __restrict__ tt4)           // [M] (-2tx, -2ty, -2tz, ||t||^2)
{
    const int i = blockIdx.x * 256 + threadIdx.x;
    if (i < MM) {
        const float tx = target[i * 3 + 0];
        const float ty = target[i * 3 + 1];
        const float tz = target[i * 3 + 2];
        tt4[i] = make_float4(-2.0f * tx, -2.0f * ty, -2.0f * tz,
                             fmaf(tx, tx, fmaf(ty, ty, tz * tz)));
    }
}

__global__ __launch_bounds__(256, 8) void binder_pair_kernel(
    const float* __restrict__ binder,    // [B, N, 3]
    const float4* __restrict__ tt4,      // [M] transformed targets
    float* __restrict__ min_part,        // [B, SL, N] partial min d^2
    float* __restrict__ repel_part)      // [B, SL]
{
    __shared__ float wred[4];

    const int s   = blockIdx.x;
    const int b   = blockIdx.y;
    const int tid = threadIdx.x;

    // 4 binder points per thread; 48B contiguous/lane, 16B-aligned.
    const float* bp = binder + ((size_t)b * NN + tid * 4) * 3;
    const float4 f0 = ((const float4*)bp)[0];
    const float4 f1 = ((const float4*)bp)[1];
    const float4 f2 = ((const float4*)bp)[2];
    const float x0 = f0.x, y0 = f0.y, z0 = f0.z;
    const float x1 = f0.w, y1 = f1.x, z1 = f1.y;
    const float x2 = f1.z, y2 = f1.w, z2 = f2.x;
    const float x3 = f2.y, y3 = f2.z, z3 = f2.w;

    const float bb0 = fmaf(x0, x0, fmaf(y0, y0, z0 * z0));
    const float bb1 = fmaf(x1, x1, fmaf(y1, y1, z1 * z1));
    const float bb2 = fmaf(x2, x2, fmaf(y2, y2, z2 * z2));
    const float bb3 = fmaf(x3, x3, fmaf(y3, y3, z3 * z3));
    const float th0 = 9.0f - bb0, th1 = 9.0f - bb1;
    const float th2 = 9.0f - bb2, th3 = 9.0f - bb3;

    float m0 = 3.4e38f, m1 = 3.4e38f, m2 = 3.4e38f, m3 = 3.4e38f;
    float repel = 0.0f;

    // uniform base pointer: loop index is scalar -> s_load_dwordx4 (SMEM pipe)
    const float4* tt = tt4 + (size_t)s * MSL;
#pragma unroll 4
    for (int m = 0; m < MSL; ++m) {
        const float4 t = tt[m];   // wave-uniform global -> scalar load, L2-hot
        const float e0 = fmaf(x0, t.x, fmaf(y0, t.y, fmaf(z0, t.z, t.w)));
        const float e1 = fmaf(x1, t.x, fmaf(y1, t.y, fmaf(z1, t.z, t.w)));
        const float e2 = fmaf(x2, t.x, fmaf(y2, t.y, fmaf(z2, t.z, t.w)));
        const float e3 = fmaf(x3, t.x, fmaf(y3, t.y, fmaf(z3, t.z, t.w)));
        m0 = fminf(m0, e0);
        m1 = fminf(m1, e1);
        m2 = fminf(m2, e2);
        m3 = fminf(m3, e3);
        // per-point clash: e < 9-bb <=> d^2 < 9; non-clash lanes clamp to 0.
        if (__any(e0 < th0)) {
            const float c = fmaxf(3.0f - __builtin_amdgcn_sqrtf(fmaxf(bb0 + e0, 0.0f)), 0.0f);
            repel = fmaf(c, c, repel);
        }
        if (__any(e1 < th1)) {
            const float c = fmaxf(3.0f - __builtin_amdgcn_sqrtf(fmaxf(bb1 + e1, 0.0f)), 0.0f);
            repel = fmaf(c, c, repel);
        }
        if (__any(e2 < th2)) {
            const float c = fmaxf(3.0f - __builtin_amdgcn_sqrtf(fmaxf(bb2 + e2, 0.0f)), 0.0f);
            repel = fmaf(c, c, repel);
        }
        if (__any(e3 < th3)) {
            const float c = fmaxf(3.0f - __builtin_amdgcn_sqrtf(fmaxf(bb3 + e3, 0.0f)), 0.0f);
            repel = fmaf(c, c, repel);
        }
    }

    // plain coalesced store of this slice's partial min d^2 (no atomics)
    float4* op = (float4*)(min_part + ((size_t)b * SL + s) * NN) + tid;
    *op = make_float4(fmaxf(bb0 + m0, 0.0f), fmaxf(bb1 + m1, 0.0f),
                      fmaxf(bb2 + m2, 0.0f), fmaxf(bb3 + m3, 0.0f));

    // repel block-reduce: wave shuffle then 4-slot LDS
#pragma unroll
    for (int off = 32; off > 0; off >>= 1) repel += __shfl_down(repel, off);
    if ((tid & 63) == 0) wred[tid >> 6] = repel;
    __syncthreads();
    if (tid == 0) repel_part[b * SL + s] = wred[0] + wred[1] + wred[2] + wred[3];
}

__global__ __launch_bounds__(256) void binder_fold_kernel(
    const float* __restrict__ min_part,  // [B, SL, N]
    float* __restrict__ min_d2)          // [B, N]
{
    __shared__ float pe[256];
    const int nc  = blockIdx.x;          // 16 n-chunks of 64 points
    const int b   = blockIdx.y;
    const int tid = threadIdx.x;
    const int n   = nc * 64 + (tid & 63);
    const int sg  = tid >> 6;            // 4 slice-groups of 32

    const float* base = min_part + (size_t)b * SL * NN + n;
    float mn = 3.4e38f;
#pragma unroll 8
    for (int s = sg * 32; s < sg * 32 + 32; ++s)
        mn = fminf(mn, base[(size_t)s * NN]);
    pe[tid] = mn;
    __syncthreads();
    if (tid < 64) {
        const float v = fminf(fminf(pe[tid], pe[tid + 64]),
                              fminf(pe[tid + 128], pe[tid + 192]));
        min_d2[(size_t)b * NN + nc * 64 + tid] = v;
    }
}

__global__ __launch_bounds__(256) void binder_select_kernel(
    const float* __restrict__ min_d2,      // [B, N] (nonneg -> bits monotonic)
    const float* __restrict__ repel_part,  // [B, SL]
    float* __restrict__ out)               // [B]
{
    __shared__ int cnt[256];
    __shared__ int wsum[4];
    __shared__ int bc_bin, bc_rem;
    __shared__ float wred[4];
    __shared__ float wred2[4];

    const int b    = blockIdx.x;
    const int tid  = threadIdx.x;
    const int lane = tid & 63;
    const int wid  = tid >> 6;

    const uint4 kv = ((const uint4*)(min_d2 + (size_t)b * NN))[tid];
    const unsigned uu[4] = {kv.x, kv.y, kv.z, kv.w};

    // radix-256 select of the KSEL-th smallest d^2 bit pattern, MSB-first.
    // scan per round: intra-wave __shfl_up inclusive scan (no barriers) +
    // 4-entry wave-sum combine -> 4 barriers/round.
    unsigned prefix = 0u;
    int rem = KSEL;
#pragma unroll
    for (int shift = 24; shift >= 0; shift -= 8) {
        cnt[tid] = 0;
        __syncthreads();
        const unsigned hmask = (shift == 24) ? 0u : (0xFFFFFFFFu << (shift + 8));
#pragma unroll
        for (int p = 0; p < 4; ++p)
            if ((uu[p] & hmask) == (prefix & hmask))
                atomicAdd(&cnt[(uu[p] >> shift) & 255], 1);
        __syncthreads();
        const int orig = cnt[tid];
        int v = orig;
#pragma unroll
        for (int s = 1; s < 64; s <<= 1) {
            const int t = __shfl_up(v, s);
            if (lane >= s) v += t;
        }
        if (lane == 63) wsum[wid] = v;
        __syncthreads();
        int off = 0;
        for (int w = 0; w < wid; ++w) off += wsum[w];
        const int incl = v + off;
        const int excl = incl - orig;
        if (rem > excl && rem <= incl) {   // unique tid (orig>0 there)
            bc_bin = tid;
            bc_rem = rem - excl;
        }
        __syncthreads();
        prefix |= ((unsigned)bc_bin) << shift;
        rem = bc_rem;
        __syncthreads();
    }
    // prefix = T (exact bits of KSEL-th smallest d2); rem = #ties to take.

    float local = 0.0f;
#pragma unroll
    for (int p = 0; p < 4; ++p)
        if (uu[p] < prefix) local += __builtin_amdgcn_sqrtf(__uint_as_float(uu[p]));
#pragma unroll
    for (int off = 32; off > 0; off >>= 1) local += __shfl_down(local, off);
    if ((tid & 63) == 0) wred[tid >> 6] = local;

    float r = (tid < SL) ? repel_part[b * SL + tid] : 0.0f;
#pragma unroll
    for (int off = 32; off > 0; off >>= 1) r += __shfl_down(r, off);
    if ((tid & 63) == 0) wred2[tid >> 6] = r;
    __syncthreads();

    if (tid == 0) {
        const float total = wred[0] + wred[1] + wred[2] + wred[3]
                          + (float)rem * __builtin_amdgcn_sqrtf(__uint_as_float(prefix));
        const float rp = wred2[0] + wred2[1] + wred2[2] + wred2[3];
        out[b] = 10.0f * (total / (float)KSEL) + 5.0f * rp;
    }
}

extern "C" void kernel_launch(void* const* d_in, const int* in_sizes, int n_in,
                              void* d_out, int out_size, void* d_ws, size_t ws_size,
                              hipStream_t stream) {
    const float* binder = (const float*)d_in[0];   // [16,1024,3] fp32
    const float* target = (const float*)d_in[1];   // [8192,3]   fp32
    float* out = (float*)d_out;                    // [16]       fp32

    // workspace layout: tt4 128KB | min_part 8MB | repel_part 8KB | min_d2 64KB
    char* ws = (char*)d_ws;
    float4* tt4       = (float4*)ws;                                ws += (size_t)MM * sizeof(float4);
    float*  min_part  = (float*)ws;                                 ws += (size_t)BB * SL * NN * sizeof(float);
    float*  repel_part= (float*)ws;                                 ws += (size_t)BB * SL * sizeof(float);
    float*  min_d2    = (float*)ws;

    target_transform_kernel<<<MM / 256, 256, 0, stream>>>(target, tt4);
    dim3 g1(SL, BB);   // 128 x 16 = 2048 blocks -> 8 blocks/CU, 8 waves/SIMD
    binder_pair_kernel<<<g1, 256, 0, stream>>>(binder, tt4, min_part, repel_part);
    dim3 g2(16, BB);   // 256 blocks
    binder_fold_kernel<<<g2, 256, 0, stream>>>(min_part, min_d2);
    binder_select_kernel<<<BB, 256, 0, stream>>>(min_d2, repel_part, out);
}

// Round 8
// 90.894 us; speedup vs baseline: 1.0219x; 1.0219x over previous
//
#include <hip/hip_runtime.h>

// B=16, N=1024, M=8192.
//   d[b,n,m] = || binder[b,n,:] - target[m,:] ||
//   attract[b] = mean of 204 smallest (min_m d) over n;  repel[b] = sum relu(3-d)^2
//   out[b] = 10*attract + 5*repel
//
// R10 (R9 post-mortem: scalar-pipe move NEUTRAL on pair, and +2 dispatches
// cost ~4us -> total regressed 89.1->92.9. Fill is a fixed 41us harness
// poison of the whole 256MiB workspace; dispatch count is first-order):
//  - back to R8's proven 2-kernel structure (LDS-staged targets, streaming
//    stores, fold-in-reduce).
//  - pair: 2 batches per block (8 pts/thread from b0,b1). Same staged tile
//    serves both -> total ds_read_b128 HALVES (~10->~5us/CU LDS issue) while
//    dependent VALU per read doubles (8 indep chains hide LDS latency at
//    4 waves/SIMD). grid (128,8)=1024 blocks, 4 blocks/CU, 16 waves/CU.

#define BB 16
#define NN 1024
#define MM 8192
#define SL 128              // M-slices
#define MSL (MM / SL)       // 64 targets per slice
#define PB 2                // batches per block
#define KSEL 204            // int(0.2 * 1024)

__global__ __launch_bounds__(256, 4) void binder_pair_kernel(
    const float* __restrict__ binder,    // [B, N, 3]
    const float* __restrict__ target,    // [M, 3]
    float* __restrict__ min_part,        // [B, SL, N] partial min d^2
    float* __restrict__ repel_part)      // [B, SL]
{
    __shared__ float4 t4[MSL];           // 1KB: (-2tx, -2ty, -2tz, ||t||^2)
    __shared__ float wred0[4];
    __shared__ float wred1[4];

    const int s   = blockIdx.x;
    const int b0  = blockIdx.y * PB;
    const int b1  = b0 + 1;
    const int tid = threadIdx.x;

    if (tid < MSL) {
        const float* tp = target + (size_t)(s * MSL + tid) * 3;
        const float tx = tp[0], ty = tp[1], tz = tp[2];
        t4[tid] = make_float4(-2.0f * tx, -2.0f * ty, -2.0f * tz,
                              fmaf(tx, tx, fmaf(ty, ty, tz * tz)));
    }
    __syncthreads();

    // 4 binder points per thread per batch; 48B contiguous/lane, 16B-aligned.
    const float* bpA = binder + ((size_t)b0 * NN + tid * 4) * 3;
    const float4 a0 = ((const float4*)bpA)[0];
    const float4 a1 = ((const float4*)bpA)[1];
    const float4 a2 = ((const float4*)bpA)[2];
    const float* bpB = binder + ((size_t)b1 * NN + tid * 4) * 3;
    const float4 c0 = ((const float4*)bpB)[0];
    const float4 c1 = ((const float4*)bpB)[1];
    const float4 c2 = ((const float4*)bpB)[2];

    const float ax0 = a0.x, ay0 = a0.y, az0 = a0.z;
    const float ax1 = a0.w, ay1 = a1.x, az1 = a1.y;
    const float ax2 = a1.z, ay2 = a1.w, az2 = a2.x;
    const float ax3 = a2.y, ay3 = a2.z, az3 = a2.w;
    const float bx0 = c0.x, by0 = c0.y, bz0 = c0.z;
    const float bx1 = c0.w, by1 = c1.x, bz1 = c1.y;
    const float bx2 = c1.z, by2 = c1.w, bz2 = c2.x;
    const float bx3 = c2.y, by3 = c2.z, bz3 = c2.w;

    const float abb0 = fmaf(ax0, ax0, fmaf(ay0, ay0, az0 * az0));
    const float abb1 = fmaf(ax1, ax1, fmaf(ay1, ay1, az1 * az1));
    const float abb2 = fmaf(ax2, ax2, fmaf(ay2, ay2, az2 * az2));
    const float abb3 = fmaf(ax3, ax3, fmaf(ay3, ay3, az3 * az3));
    const float bbb0 = fmaf(bx0, bx0, fmaf(by0, by0, bz0 * bz0));
    const float bbb1 = fmaf(bx1, bx1, fmaf(by1, by1, bz1 * bz1));
    const float bbb2 = fmaf(bx2, bx2, fmaf(by2, by2, bz2 * bz2));
    const float bbb3 = fmaf(bx3, bx3, fmaf(by3, by3, bz3 * bz3));
    const float ath0 = 9.0f - abb0, ath1 = 9.0f - abb1;
    const float ath2 = 9.0f - abb2, ath3 = 9.0f - abb3;
    const float bth0 = 9.0f - bbb0, bth1 = 9.0f - bbb1;
    const float bth2 = 9.0f - bbb2, bth3 = 9.0f - bbb3;

    float am0 = 3.4e38f, am1 = 3.4e38f, am2 = 3.4e38f, am3 = 3.4e38f;
    float bm0 = 3.4e38f, bm1 = 3.4e38f, bm2 = 3.4e38f, bm3 = 3.4e38f;
    float repel0 = 0.0f, repel1 = 0.0f;

#pragma unroll 4
    for (int m = 0; m < MSL; ++m) {
        const float4 t = t4[m];   // wave-uniform addr -> broadcast b128
        const float ae0 = fmaf(ax0, t.x, fmaf(ay0, t.y, fmaf(az0, t.z, t.w)));
        const float ae1 = fmaf(ax1, t.x, fmaf(ay1, t.y, fmaf(az1, t.z, t.w)));
        const float ae2 = fmaf(ax2, t.x, fmaf(ay2, t.y, fmaf(az2, t.z, t.w)));
        const float ae3 = fmaf(ax3, t.x, fmaf(ay3, t.y, fmaf(az3, t.z, t.w)));
        const float be0 = fmaf(bx0, t.x, fmaf(by0, t.y, fmaf(bz0, t.z, t.w)));
        const float be1 = fmaf(bx1, t.x, fmaf(by1, t.y, fmaf(bz1, t.z, t.w)));
        const float be2 = fmaf(bx2, t.x, fmaf(by2, t.y, fmaf(bz2, t.z, t.w)));
        const float be3 = fmaf(bx3, t.x, fmaf(by3, t.y, fmaf(bz3, t.z, t.w)));
        am0 = fminf(am0, ae0);
        am1 = fminf(am1, ae1);
        am2 = fminf(am2, ae2);
        am3 = fminf(am3, ae3);
        bm0 = fminf(bm0, be0);
        bm1 = fminf(bm1, be1);
        bm2 = fminf(bm2, be2);
        bm3 = fminf(bm3, be3);
        // per-point clash: e < 9-bb <=> d^2 < 9; non-clash lanes clamp to 0.
        if (__any(ae0 < ath0)) {
            const float c = fmaxf(3.0f - __builtin_amdgcn_sqrtf(fmaxf(abb0 + ae0, 0.0f)), 0.0f);
            repel0 = fmaf(c, c, repel0);
        }
        if (__any(ae1 < ath1)) {
            const float c = fmaxf(3.0f - __builtin_amdgcn_sqrtf(fmaxf(abb1 + ae1, 0.0f)), 0.0f);
            repel0 = fmaf(c, c, repel0);
        }
        if (__any(ae2 < ath2)) {
            const float c = fmaxf(3.0f - __builtin_amdgcn_sqrtf(fmaxf(abb2 + ae2, 0.0f)), 0.0f);
            repel0 = fmaf(c, c, repel0);
        }
        if (__any(ae3 < ath3)) {
            const float c = fmaxf(3.0f - __builtin_amdgcn_sqrtf(fmaxf(abb3 + ae3, 0.0f)), 0.0f);
            repel0 = fmaf(c, c, repel0);
        }
        if (__any(be0 < bth0)) {
            const float c = fmaxf(3.0f - __builtin_amdgcn_sqrtf(fmaxf(bbb0 + be0, 0.0f)), 0.0f);
            repel1 = fmaf(c, c, repel1);
        }
        if (__any(be1 < bth1)) {
            const float c = fmaxf(3.0f - __builtin_amdgcn_sqrtf(fmaxf(bbb1 + be1, 0.0f)), 0.0f);
            repel1 = fmaf(c, c, repel1);
        }
        if (__any(be2 < bth2)) {
            const float c = fmaxf(3.0f - __builtin_amdgcn_sqrtf(fmaxf(bbb2 + be2, 0.0f)), 0.0f);
            repel1 = fmaf(c, c, repel1);
        }
        if (__any(be3 < bth3)) {
            const float c = fmaxf(3.0f - __builtin_amdgcn_sqrtf(fmaxf(bbb3 + be3, 0.0f)), 0.0f);
            repel1 = fmaf(c, c, repel1);
        }
    }

    // plain coalesced stores of both batches' partial min d^2 (no atomics)
    float4* opA = (float4*)(min_part + ((size_t)b0 * SL + s) * NN) + tid;
    *opA = make_float4(fmaxf(abb0 + am0, 0.0f), fmaxf(abb1 + am1, 0.0f),
                       fmaxf(abb2 + am2, 0.0f), fmaxf(abb3 + am3, 0.0f));
    float4* opB = (float4*)(min_part + ((size_t)b1 * SL + s) * NN) + tid;
    *opB = make_float4(fmaxf(bbb0 + bm0, 0.0f), fmaxf(bbb1 + bm1, 0.0f),
                       fmaxf(bbb2 + bm2, 0.0f), fmaxf(bbb3 + bm3, 0.0f));

    // repel block-reduce: wave shuffle then 4-slot LDS, per batch
#pragma unroll
    for (int off = 32; off > 0; off >>= 1) {
        repel0 += __shfl_down(repel0, off);
        repel1 += __shfl_down(repel1, off);
    }
    if ((tid & 63) == 0) {
        wred0[tid >> 6] = repel0;
        wred1[tid >> 6] = repel1;
    }
    __syncthreads();
    if (tid == 0)
        repel_part[b0 * SL + s] = wred0[0] + wred0[1] + wred0[2] + wred0[3];
    if (tid == 1)
        repel_part[b1 * SL + s] = wred1[0] + wred1[1] + wred1[2] + wred1[3];
}

__global__ __launch_bounds__(256) void binder_reduce_kernel(
    const float* __restrict__ min_part,    // [B, SL, N]
    const float* __restrict__ repel_part,  // [B, SL]
    float* __restrict__ out)               // [B]
{
    __shared__ int cnt[256];
    __shared__ int wsum[4];
    __shared__ int bc_bin, bc_rem;
    __shared__ float wred[4];
    __shared__ float wred2[4];

    const int b    = blockIdx.x;
    const int tid  = threadIdx.x;
    const int lane = tid & 63;
    const int wid  = tid >> 6;

    // fold the SL slice partials during load (each iter = one coalesced 4KB row)
    const float* base = min_part + (size_t)b * SL * NN;
    float mn0 = 3.4e38f, mn1 = 3.4e38f, mn2 = 3.4e38f, mn3 = 3.4e38f;
#pragma unroll 8
    for (int s = 0; s < SL; ++s) {
        const float4 v = ((const float4*)(base + (size_t)s * NN))[tid];
        mn0 = fminf(mn0, v.x);
        mn1 = fminf(mn1, v.y);
        mn2 = fminf(mn2, v.z);
        mn3 = fminf(mn3, v.w);
    }
    const unsigned uu[4] = {__float_as_uint(mn0), __float_as_uint(mn1),
                            __float_as_uint(mn2), __float_as_uint(mn3)};

    // radix-256 select of the KSEL-th smallest d^2 bit pattern, MSB-first.
    // scan per round: intra-wave __shfl_up inclusive scan (no barriers) +
    // 4-entry wave-sum combine -> 4 barriers/round.
    unsigned prefix = 0u;
    int rem = KSEL;
#pragma unroll
    for (int shift = 24; shift >= 0; shift -= 8) {
        cnt[tid] = 0;
        __syncthreads();
        const unsigned hmask = (shift == 24) ? 0u : (0xFFFFFFFFu << (shift + 8));
#pragma unroll
        for (int p = 0; p < 4; ++p)
            if ((uu[p] & hmask) == (prefix & hmask))
                atomicAdd(&cnt[(uu[p] >> shift) & 255], 1);
        __syncthreads();
        const int orig = cnt[tid];
        int v = orig;
#pragma unroll
        for (int s = 1; s < 64; s <<= 1) {
            const int t = __shfl_up(v, s);
            if (lane >= s) v += t;
        }
        if (lane == 63) wsum[wid] = v;
        __syncthreads();
        int off = 0;
        for (int w = 0; w < wid; ++w) off += wsum[w];
        const int incl = v + off;
        const int excl = incl - orig;
        if (rem > excl && rem <= incl) {   // unique tid (orig>0 there)
            bc_bin = tid;
            bc_rem = rem - excl;
        }
        __syncthreads();
        prefix |= ((unsigned)bc_bin) << shift;
        rem = bc_rem;
        __syncthreads();
    }
    // prefix = T (exact bits of KSEL-th smallest d2); rem = #ties to take.

    float local = 0.0f;
#pragma unroll
    for (int p = 0; p < 4; ++p)
        if (uu[p] < prefix) local += __builtin_amdgcn_sqrtf(__uint_as_float(uu[p]));
#pragma unroll
    for (int off = 32; off > 0; off >>= 1) local += __shfl_down(local, off);
    if ((tid & 63) == 0) wred[tid >> 6] = local;

    float r = (tid < SL) ? repel_part[b * SL + tid] : 0.0f;
#pragma unroll
    for (int off = 32; off > 0; off >>= 1) r += __shfl_down(r, off);
    if ((tid & 63) == 0) wred2[tid >> 6] = r;
    __syncthreads();

    if (tid == 0) {
        const float total = wred[0] + wred[1] + wred[2] + wred[3]
                          + (float)rem * __builtin_amdgcn_sqrtf(__uint_as_float(prefix));
        const float rp = wred2[0] + wred2[1] + wred2[2] + wred2[3];
        out[b] = 10.0f * (total / (float)KSEL) + 5.0f * rp;
    }
}

extern "C" void kernel_launch(void* const* d_in, const int* in_sizes, int n_in,
                              void* d_out, int out_size, void* d_ws, size_t ws_size,
                              hipStream_t stream) {
    const float* binder = (const float*)d_in[0];   // [16,1024,3] fp32
    const float* target = (const float*)d_in[1];   // [8192,3]   fp32
    float* out = (float*)d_out;                    // [16]       fp32

    // workspace: min_part 8MB + repel_part 8KB
    float* min_part   = (float*)d_ws;
    float* repel_part = (float*)((char*)d_ws + (size_t)BB * SL * NN * sizeof(float));

    dim3 g1(SL, BB / PB);  // 128 x 8 = 1024 blocks -> 4 blocks/CU, 16 waves/CU
    binder_pair_kernel<<<g1, 256, 0, stream>>>(binder, target, min_part, repel_part);
    binder_reduce_kernel<<<BB, 256, 0, stream>>>(min_part, repel_part, out);
}